// Round 6
// baseline (6265.871 us; speedup 1.0000x reference)
//
#include <hip/hip_runtime.h>
#include <hip/hip_bf16.h>

// ---------- types / constants ----------
typedef short bf16x8 __attribute__((ext_vector_type(8)));
typedef float f32x4 __attribute__((ext_vector_type(4)));
typedef float f32x2 __attribute__((ext_vector_type(2)));

#define B_   16
#define LSEQ 4096
#define DM   512
#define NST  32
#define NL   4
#define NCH  16      // chunks over L
#define TC   256     // chunk length (NCH*TC == LSEQ)
#define SZC  (NL*NST*DM)   // elems per coef plane = 65536

__device__ __forceinline__ unsigned short f2us(float f){
  unsigned int x = __float_as_uint(f);
  x += 0x7fff + ((x >> 16) & 1);      // round-to-nearest-even
  return (unsigned short)(x >> 16);
}
__device__ __forceinline__ f32x2 mk2(float a, float b){ f32x2 r; r.x = a; r.y = b; return r; }

// complex step: s' = w*s + u  (w,s complex as (re,im), u real)
// s'.re = wr*sr - wi*si + u ; s'.im = wr*si + wi*sr
__device__ __forceinline__ f32x2 cstep(f32x2 wrr, f32x2 wnn, f32x2 s, f32x2 u2){
  f32x2 sw; sw.x = s.y; sw.y = s.x;
  return wrr * s + (wnn * sw + u2);
}

// ---------- K0: per-layer SSM coefficients ----------
// coef planes: 0 wre, 1 wim, 2 2*Re(Cc), 3 -2*Im(Cc), 4 wT_re, 5 wT_im ; layout [ly][n][h]
__global__ void k_coef(const float* log_dt, const float* C_re,
                       const float* C_im, const float* lAr,
                       const float* Aimg, float* coef){
  int tid = blockIdx.x * 256 + threadIdx.x;          // (ly*NST + n)*DM + h
  if (tid >= NL*NST*DM) return;
  int h  = tid & (DM-1);
  int n  = (tid >> 9) & (NST-1);
  int ly = tid >> 14;
  int ihn = (ly*DM + h)*NST + n;                     // input layout (ly,h,n)
  float dt  = expf(log_dt[ly*DM + h]);
  float Are = -expf(lAr[ihn]);
  float Aim = Aimg[ihn];
  float dar = dt*Are, dai = dt*Aim;
  float er  = expf(dar);
  float wre = er*cosf(dai), wim = er*sinf(dai);
  float Cr  = C_re[ihn], Ci = C_im[ihn];
  float e1r = wre - 1.0f, e1i = wim;
  float tr = Cr*e1r - Ci*e1i;
  float ti = Cr*e1i + Ci*e1r;
  float inv = 1.0f/(Are*Are + Aim*Aim);
  float ccr = (tr*Are + ti*Aim)*inv;
  float cci = (ti*Are - tr*Aim)*inv;
  float eT = expf(dar*(float)TC);
  float aT = dai*(float)TC;
  coef[0*SZC + tid] = wre;
  coef[1*SZC + tid] = wim;
  coef[2*SZC + tid] = 2.0f*ccr;
  coef[3*SZC + tid] = -2.0f*cci;
  coef[4*SZC + tid] = eT*cosf(aT);
  coef[5*SZC + tid] = eT*sinf(aT);
}

// ---------- K0b: Wconv fp32 -> bf16 (all layers) ----------
__global__ void k_cvt(const float* Wc, unsigned short* Wcb){
  int tid = blockIdx.x * 256 + threadIdx.x;          // ×8 elems
  const float4 a = *(const float4*)(Wc + (size_t)tid*8);
  const float4 b = *(const float4*)(Wc + (size_t)tid*8 + 4);
  ushort4 r0, r1;
  r0.x = f2us(a.x); r0.y = f2us(a.y); r0.z = f2us(a.z); r0.w = f2us(a.w);
  r1.x = f2us(b.x); r1.y = f2us(b.y); r1.z = f2us(b.z); r1.w = f2us(b.w);
  *(ushort4*)(Wcb + (size_t)tid*8)     = r0;
  *(ushort4*)(Wcb + (size_t)tid*8 + 4) = r1;
}

// ---------- K1a: pz[b,d] = z @ Wp^T + bp ----------
__global__ void k_proj(const float* z, const float* Wp,
                       const float* bp, float* pz){
  int tid = blockIdx.x * 256 + threadIdx.x;          // b*DM + d
  if (tid >= B_*DM) return;
  int d = tid & (DM-1), b = tid >> 9;
  float acc = bp[d];
  const float* zr = z  + b*256;
  const float* wr = Wp + d*256;
  for (int k = 0; k < 256; ++k) acc = fmaf(zr[k], wr[k], acc);
  pz[tid] = acc;
}

// ---------- K1b: x[b,l,d] = pz[b,d] + pos[l,d] (fp32) ----------
__global__ void k_bcast(const float* pz, const float* pos, float* x){
  int tid = blockIdx.x * 256 + threadIdx.x;          // over elems/4
  size_t idx = (size_t)tid * 4;
  int d = idx & 511;
  int l = (idx >> 9) & 4095;
  int b = idx >> 21;
  float4 p = *(const float4*)(pz + b*DM + d);
  float4 pe = *(const float4*)(pos + (size_t)l*DM + d);
  float4 r;
  r.x = p.x + pe.x; r.y = p.y + pe.y;
  r.z = p.z + pe.z; r.w = p.w + pe.w;
  *(float4*)(x + idx) = r;
}

// ---------- K2: pass-1 — local chunk end states ----------
// thread = (b, c, h); 32 complex states per thread; t unrolled x4.
// waves_per_eu(2,2): pin occupancy target to 2 waves/SIMD -> 256-VGPR budget, no spills.
__global__ __launch_bounds__(256) __attribute__((amdgpu_waves_per_eu(2,2)))
void k_pass1(const float* __restrict__ x, const float* __restrict__ coef,
             float* __restrict__ states, int ly){
  int tid = blockIdx.x * 256 + threadIdx.x;          // (b*NCH + c)*DM + h
  int h = tid & (DM-1);
  int c = (tid >> 9) & (NCH-1);
  int b = tid >> 13;
  f32x2 wv[NST], sv[NST];
  #pragma unroll
  for (int n = 0; n < NST; ++n){
    int o = ((ly*NST + n) << 9) + h;
    wv[n] = mk2(coef[0*SZC + o], coef[1*SZC + o]);
    sv[n] = mk2(0.f, 0.f);
  }
  const float* up = x + (size_t)((b << 12) + c*TC) * DM + h;
  for (int t0 = 0; t0 < TC; t0 += 4){
    f32x2 u0 = mk2(up[(size_t)(t0+0) << 9], 0.f);
    f32x2 u1 = mk2(up[(size_t)(t0+1) << 9], 0.f);
    f32x2 u2 = mk2(up[(size_t)(t0+2) << 9], 0.f);
    f32x2 u3 = mk2(up[(size_t)(t0+3) << 9], 0.f);
    #pragma unroll
    for (int n = 0; n < NST; ++n){
      f32x2 w = wv[n];
      f32x2 wrr = mk2(w.x, w.x);
      f32x2 wnn = mk2(-w.y, w.y);
      f32x2 s = sv[n];
      s = cstep(wrr, wnn, s, u0);
      s = cstep(wrr, wnn, s, u1);
      s = cstep(wrr, wnn, s, u2);
      s = cstep(wrr, wnn, s, u3);
      sv[n] = s;
    }
  }
  float* sp = states + (size_t)((b*NCH + c)*64) * DM + h;
  #pragma unroll
  for (int n = 0; n < NST; ++n){
    sp[n << 9]          = sv[n].x;
    sp[(NST + n) << 9]  = sv[n].y;
  }
}

// ---------- K3: scan over chunks -> start states (in place) ----------
__global__ void k_scan(const float* coef, float* states, int ly){
  int tid = blockIdx.x * 256 + threadIdx.x;          // (b*NST + n)*DM + h
  int h = tid & (DM-1);
  int n = (tid >> 9) & (NST-1);
  int b = tid >> 14;
  int o = ((ly*NST + n) << 9) + h;
  float wTre = coef[4*SZC + o];
  float wTim = coef[5*SZC + o];
  float Sre = 0.f, Sim = 0.f;
  for (int c = 0; c < NCH; ++c){
    float* pr = states + (size_t)((b*NCH + c)*64 + n) * DM + h;
    float lr = pr[0];
    float li = pr[NST << 9];
    pr[0]         = Sre;           // start state for chunk c
    pr[NST << 9]  = Sim;
    float nr = fmaf(wTre, Sre, fmaf(-wTim, Sim, lr));
    float ni = fmaf(wTre, Sim, fmaf( wTim, Sre, li));
    Sre = nr; Sim = ni;
  }
}

// ---------- K4: pass-2 — replay + y + D-skip + GELU -> ybuf (bf16) ----------
__global__ __launch_bounds__(256) __attribute__((amdgpu_waves_per_eu(2,2)))
void k_pass2(const float* __restrict__ x, const float* __restrict__ coef,
             const float* __restrict__ states, const float* __restrict__ Dsk,
             unsigned short* __restrict__ ybuf, int ly){
  int tid = blockIdx.x * 256 + threadIdx.x;          // (b*NCH + c)*DM + h
  int h = tid & (DM-1);
  int c = (tid >> 9) & (NCH-1);
  int b = tid >> 13;
  f32x2 wv[NST], cv[NST], sv[NST];
  const float* sp = states + (size_t)((b*NCH + c)*64) * DM + h;
  #pragma unroll
  for (int n = 0; n < NST; ++n){
    int o = ((ly*NST + n) << 9) + h;
    wv[n] = mk2(coef[0*SZC + o], coef[1*SZC + o]);
    cv[n] = mk2(coef[2*SZC + o], coef[3*SZC + o]);   // (2Re, -2Im)
    sv[n] = mk2(sp[n << 9], sp[(NST + n) << 9]);
  }
  float Dv = Dsk[ly*DM + h];
  const float* up = x + (size_t)((b << 12) + c*TC) * DM + h;
  unsigned short* yp = ybuf + (size_t)((b << 12) + c*TC) * DM + h;
  for (int t0 = 0; t0 < TC; t0 += 4){
    float ur0 = up[(size_t)(t0+0) << 9];
    float ur1 = up[(size_t)(t0+1) << 9];
    float ur2 = up[(size_t)(t0+2) << 9];
    float ur3 = up[(size_t)(t0+3) << 9];
    f32x2 u0 = mk2(ur0, 0.f), u1 = mk2(ur1, 0.f), u2 = mk2(ur2, 0.f), u3 = mk2(ur3, 0.f);
    f32x2 y0 = mk2(0.f,0.f), y1 = mk2(0.f,0.f), y2 = mk2(0.f,0.f), y3 = mk2(0.f,0.f);
    #pragma unroll
    for (int n = 0; n < NST; ++n){
      f32x2 w = wv[n], cc = cv[n];
      f32x2 wrr = mk2(w.x, w.x);
      f32x2 wnn = mk2(-w.y, w.y);
      f32x2 s = sv[n];
      s = cstep(wrr, wnn, s, u0); y0 += cc * s;
      s = cstep(wrr, wnn, s, u1); y1 += cc * s;
      s = cstep(wrr, wnn, s, u2); y2 += cc * s;
      s = cstep(wrr, wnn, s, u3); y3 += cc * s;
      sv[n] = s;
    }
    float ya = y0.x + y0.y + Dv*ur0;
    float yb = y1.x + y1.y + Dv*ur1;
    float yc = y2.x + y2.y + Dv*ur2;
    float yd = y3.x + y3.y + Dv*ur3;
    float ga = 0.5f*ya*(1.0f + erff(ya*0.70710678118654752f));
    float gb = 0.5f*yb*(1.0f + erff(yb*0.70710678118654752f));
    float gc = 0.5f*yc*(1.0f + erff(yc*0.70710678118654752f));
    float gd = 0.5f*yd*(1.0f + erff(yd*0.70710678118654752f));
    yp[(size_t)(t0+0) << 9] = f2us(ga);
    yp[(size_t)(t0+1) << 9] = f2us(gb);
    yp[(size_t)(t0+2) << 9] = f2us(gc);
    yp[(size_t)(t0+3) << 9] = f2us(gd);
  }
}

// ---------- K5: GEMM (M=B*L, N=512 x both GLU halves, K=512) + GLU + residual ----------
__global__ __launch_bounds__(256,2) void k_gemm(const unsigned short* A, const unsigned short* Bw,
                                                const float* bias, float* x, int ly){
  __shared__ short As[128*64];
  __shared__ short Bs[2][128*64];
  const int K = 512;
  int Mt = blockIdx.x >> 2;        // 512 m-tiles of 128 rows
  int Nt = blockIdx.x & 3;         // 4 n-tiles of 128 cols (each also covers +512 half)
  int lane = threadIdx.x & 63, wv = threadIdx.x >> 6;
  int wm = wv >> 1, wn = wv & 1;
  f32x4 acc[2][4][4] = {};
  const unsigned short* Ag = A  + (size_t)Mt * 128 * K;
  const unsigned short* B0 = Bw + (size_t)ly * 1024 * K + (size_t)Nt * 128 * K;
  const unsigned short* B1 = B0 + (size_t)512 * K;
  for (int k0 = 0; k0 < K; k0 += 64){
    __syncthreads();
    #pragma unroll
    for (int p = 0; p < 4; ++p){
      int e = (p*256 + threadIdx.x) * 8;     // element idx in 128x64 tile
      int row = e >> 6, k = e & 63;
      int sw = ((k >> 3) ^ (row & 7)) << 3;  // XOR swizzle, conflict-reduced reads
      *(uint4*)(&As[row*64 + sw])    = *(const uint4*)(Ag + (size_t)row*K + k0 + k);
      *(uint4*)(&Bs[0][row*64 + sw]) = *(const uint4*)(B0 + (size_t)row*K + k0 + k);
      *(uint4*)(&Bs[1][row*64 + sw]) = *(const uint4*)(B1 + (size_t)row*K + k0 + k);
    }
    __syncthreads();
    #pragma unroll
    for (int kk = 0; kk < 64; kk += 32){
      int kb = (kk >> 3) + (lane >> 4);
      bf16x8 af[4], b0[4], b1[4];
      #pragma unroll
      for (int i = 0; i < 4; ++i){
        int ra = wm*64 + i*16 + (lane & 15);
        af[i] = *(const bf16x8*)(&As[ra*64 + ((kb ^ (ra & 7)) << 3)]);
        int rb = wn*64 + i*16 + (lane & 15);
        b0[i] = *(const bf16x8*)(&Bs[0][rb*64 + ((kb ^ (rb & 7)) << 3)]);
        b1[i] = *(const bf16x8*)(&Bs[1][rb*64 + ((kb ^ (rb & 7)) << 3)]);
      }
      #pragma unroll
      for (int i = 0; i < 4; ++i)
        #pragma unroll
        for (int j = 0; j < 4; ++j){
          acc[0][i][j] = __builtin_amdgcn_mfma_f32_16x16x32_bf16(af[i], b0[j], acc[0][i][j], 0, 0, 0);
          acc[1][i][j] = __builtin_amdgcn_mfma_f32_16x16x32_bf16(af[i], b1[j], acc[1][i][j], 0, 0, 0);
        }
    }
  }
  // epilogue: bias + GLU + residual add into x (fp32, in place)
  #pragma unroll
  for (int j = 0; j < 4; ++j){
    int n = Nt*128 + wn*64 + j*16 + (lane & 15);       // 0..511
    float ba = bias[ly*1024 + n];
    float bg = bias[ly*1024 + 512 + n];
    #pragma unroll
    for (int i = 0; i < 4; ++i){
      int mb = Mt*128 + wm*64 + i*16 + ((lane >> 4) << 2);
      #pragma unroll
      for (int q = 0; q < 4; ++q){
        float a = acc[0][i][j][q] + ba;
        float g = acc[1][i][j][q] + bg;
        float glu = a / (1.0f + expf(-g));
        size_t off = (size_t)(mb + q) * DM + n;
        x[off] += glu;
      }
    }
  }
}

// ---------- K7: LayerNorm over D (wave per row) ----------
__global__ __launch_bounds__(256) void k_ln(float* x, const float* gam,
                                            const float* bet, int ly){
  int row = blockIdx.x*4 + (threadIdx.x >> 6);
  int lane = threadIdx.x & 63;
  float* xr = x + (size_t)row * DM + lane*8;
  float4 v0 = *(const float4*)xr;
  float4 v1 = *(const float4*)(xr + 4);
  float s  = v0.x+v0.y+v0.z+v0.w + v1.x+v1.y+v1.z+v1.w;
  float s2 = v0.x*v0.x+v0.y*v0.y+v0.z*v0.z+v0.w*v0.w
           + v1.x*v1.x+v1.y*v1.y+v1.z*v1.z+v1.w*v1.w;
  #pragma unroll
  for (int m = 32; m > 0; m >>= 1){
    s  += __shfl_xor(s,  m, 64);
    s2 += __shfl_xor(s2, m, 64);
  }
  float mu  = s * (1.0f/DM);
  float var = s2 * (1.0f/DM) - mu*mu;
  float rs  = rsqrtf(var + 1e-5f);
  const float* gp  = gam + ly*DM + lane*8;
  const float* bp2 = bet + ly*DM + lane*8;
  float4 g0 = *(const float4*)gp,  g1 = *(const float4*)(gp + 4);
  float4 b0 = *(const float4*)bp2, b1 = *(const float4*)(bp2 + 4);
  v0.x = (v0.x-mu)*rs*g0.x + b0.x;
  v0.y = (v0.y-mu)*rs*g0.y + b0.y;
  v0.z = (v0.z-mu)*rs*g0.z + b0.z;
  v0.w = (v0.w-mu)*rs*g0.w + b0.w;
  v1.x = (v1.x-mu)*rs*g1.x + b1.x;
  v1.y = (v1.y-mu)*rs*g1.y + b1.y;
  v1.z = (v1.z-mu)*rs*g1.z + b1.z;
  v1.w = (v1.w-mu)*rs*g1.w + b1.w;
  *(float4*)xr       = v0;
  *(float4*)(xr + 4) = v1;
}

// ---------- K8: final projection to (mu, log_sig), fp32 out ----------
__global__ __launch_bounds__(256) void k_out(const float* x, const float* Wpx,
                                             const float* bpx, float* out){
  int row = blockIdx.x*4 + (threadIdx.x >> 6);        // b*4096 + l
  int lane = threadIdx.x & 63;
  const float* xr = x + (size_t)row * DM + lane*8;
  float4 v0 = *(const float4*)xr;
  float4 v1 = *(const float4*)(xr + 4);
  float p[6];
  #pragma unroll
  for (int c = 0; c < 6; ++c){
    const float* wr = Wpx + c*DM + lane*8;
    float4 w0 = *(const float4*)wr, w1 = *(const float4*)(wr + 4);
    float s = v0.x*w0.x + v0.y*w0.y + v0.z*w0.z + v0.w*w0.w
            + v1.x*w1.x + v1.y*w1.y + v1.z*w1.z + v1.w*w1.w;
    #pragma unroll
    for (int m = 32; m > 0; m >>= 1) s += __shfl_xor(s, m, 64);
    p[c] = s;
  }
  if (lane == 0){
    int b = row >> 12, l = row & 4095;
    #pragma unroll
    for (int c = 0; c < 3; ++c)
      out[((b*3 + c) << 12) + l] = p[c] + bpx[c];
    #pragma unroll
    for (int c = 3; c < 6; ++c)
      out[B_*3*LSEQ + ((b*3 + (c-3)) << 12) + l] = p[c] + bpx[c];
  }
}

// ---------- launcher ----------
extern "C" void kernel_launch(void* const* d_in, const int* in_sizes, int n_in,
                              void* d_out, int out_size, void* d_ws, size_t ws_size,
                              hipStream_t stream) {
  const float* z     = (const float*)d_in[0];
  const float* Wp    = (const float*)d_in[1];
  const float* bp    = (const float*)d_in[2];
  const float* pos   = (const float*)d_in[3];
  const float* logdt = (const float*)d_in[4];
  const float* Cre   = (const float*)d_in[5];
  const float* Cim   = (const float*)d_in[6];
  const float* lAr   = (const float*)d_in[7];
  const float* Aimg  = (const float*)d_in[8];
  const float* Dsk   = (const float*)d_in[9];
  const float* Wc    = (const float*)d_in[10];
  const float* bc    = (const float*)d_in[11];
  const float* lng   = (const float*)d_in[12];
  const float* lnb   = (const float*)d_in[13];
  const float* Wpx   = (const float*)d_in[14];
  const float* bpx   = (const float*)d_in[15];
  float* out = (float*)d_out;

  char* ws = (char*)d_ws;
  const size_t XB = (size_t)B_ * LSEQ * DM * 4;       // 134217728 : x fp32
  const size_t YB = (size_t)B_ * LSEQ * DM * 2;       // 67108864  : ybuf bf16
  const size_t SB = (size_t)B_ * NCH * 64 * DM * 4;   // 33554432  : states fp32
  const size_t CB = (size_t)6 * SZC * 4;              // 1572864   : coef
  const size_t PB = (size_t)B_ * DM * 4;              // 32768     : pz
  float*          x      = (float*)ws;
  unsigned short* ybuf   = (unsigned short*)(ws + XB);
  float*          states = (float*)(ws + XB + YB);
  float*          cf     = (float*)(ws + XB + YB + SB);
  float*          pz     = (float*)(ws + XB + YB + SB + CB);
  unsigned short* Wcb    = (unsigned short*)(ws + XB + YB + SB + CB + PB);
  // total = 240,680,960 bytes

  k_coef <<<256,   256, 0, stream>>>(logdt, Cre, Cim, lAr, Aimg, cf);
  k_cvt  <<<1024,  256, 0, stream>>>(Wc, Wcb);
  k_proj <<<32,    256, 0, stream>>>(z, Wp, bp, pz);
  k_bcast<<<32768, 256, 0, stream>>>(pz, pos, x);
  for (int ly = 0; ly < NL; ++ly){
    k_pass1<<<512,  256, 0, stream>>>(x, cf, states, ly);
    k_scan <<<1024, 256, 0, stream>>>(cf, states, ly);
    k_pass2<<<512,  256, 0, stream>>>(x, cf, states, Dsk, ybuf, ly);
    k_gemm <<<2048, 256, 0, stream>>>(ybuf, Wcb, bc, x, ly);
    k_ln   <<<16384,256, 0, stream>>>(x, lng, lnb, ly);
  }
  k_out<<<16384, 256, 0, stream>>>(x, Wpx, bpx, out);
}

// Round 7
// 1803.606 us; speedup vs baseline: 3.4741x; 3.4741x over previous
//
#include <hip/hip_runtime.h>
#include <hip/hip_bf16.h>

// ---------- types / constants ----------
typedef short bf16x8 __attribute__((ext_vector_type(8)));
typedef float f32x4 __attribute__((ext_vector_type(4)));

#define B_   16
#define LSEQ 4096
#define DM   512
#define NST  32
#define NL   4
#define NCH  16      // chunks over L
#define TC   256     // chunk length (NCH*TC == LSEQ)
#define SZC  (NL*NST*DM)   // elems per coef plane = 65536

__device__ __forceinline__ unsigned short f2us(float f){
  unsigned int x = __float_as_uint(f);
  x += 0x7fff + ((x >> 16) & 1);      // round-to-nearest-even
  return (unsigned short)(x >> 16);
}

// ---------- K0: per-layer SSM coefficients ----------
// coef planes: 0 wre, 1 wim, 2 2*Re(Cc), 3 -2*Im(Cc), 4 wT_re, 5 wT_im ; layout [ly][n][h]
__global__ void k_coef(const float* log_dt, const float* C_re,
                       const float* C_im, const float* lAr,
                       const float* Aimg, float* coef){
  int tid = blockIdx.x * 256 + threadIdx.x;          // (ly*NST + n)*DM + h
  if (tid >= NL*NST*DM) return;
  int h  = tid & (DM-1);
  int n  = (tid >> 9) & (NST-1);
  int ly = tid >> 14;
  int ihn = (ly*DM + h)*NST + n;                     // input layout (ly,h,n)
  float dt  = expf(log_dt[ly*DM + h]);
  float Are = -expf(lAr[ihn]);
  float Aim = Aimg[ihn];
  float dar = dt*Are, dai = dt*Aim;
  float er  = expf(dar);
  float wre = er*cosf(dai), wim = er*sinf(dai);
  float Cr  = C_re[ihn], Ci = C_im[ihn];
  float e1r = wre - 1.0f, e1i = wim;
  float tr = Cr*e1r - Ci*e1i;
  float ti = Cr*e1i + Ci*e1r;
  float inv = 1.0f/(Are*Are + Aim*Aim);
  float ccr = (tr*Are + ti*Aim)*inv;
  float cci = (ti*Are - tr*Aim)*inv;
  float eT = expf(dar*(float)TC);
  float aT = dai*(float)TC;
  coef[0*SZC + tid] = wre;
  coef[1*SZC + tid] = wim;
  coef[2*SZC + tid] = 2.0f*ccr;
  coef[3*SZC + tid] = -2.0f*cci;
  coef[4*SZC + tid] = eT*cosf(aT);
  coef[5*SZC + tid] = eT*sinf(aT);
}

// ---------- K0b: Wconv fp32 -> bf16 (all layers) ----------
__global__ void k_cvt(const float* Wc, unsigned short* Wcb){
  int tid = blockIdx.x * 256 + threadIdx.x;          // ×8 elems
  const float4 a = *(const float4*)(Wc + (size_t)tid*8);
  const float4 b = *(const float4*)(Wc + (size_t)tid*8 + 4);
  ushort4 r0, r1;
  r0.x = f2us(a.x); r0.y = f2us(a.y); r0.z = f2us(a.z); r0.w = f2us(a.w);
  r1.x = f2us(b.x); r1.y = f2us(b.y); r1.z = f2us(b.z); r1.w = f2us(b.w);
  *(ushort4*)(Wcb + (size_t)tid*8)     = r0;
  *(ushort4*)(Wcb + (size_t)tid*8 + 4) = r1;
}

// ---------- K1a: pz[b,d] = z @ Wp^T + bp ----------
__global__ void k_proj(const float* z, const float* Wp,
                       const float* bp, float* pz){
  int tid = blockIdx.x * 256 + threadIdx.x;          // b*DM + d
  if (tid >= B_*DM) return;
  int d = tid & (DM-1), b = tid >> 9;
  float acc = bp[d];
  const float* zr = z  + b*256;
  const float* wr = Wp + d*256;
  for (int k = 0; k < 256; ++k) acc = fmaf(zr[k], wr[k], acc);
  pz[tid] = acc;
}

// ---------- K1b: x[b,l,d] = pz[b,d] + pos[l,d] (fp32) ----------
__global__ void k_bcast(const float* pz, const float* pos, float* x){
  int tid = blockIdx.x * 256 + threadIdx.x;          // over elems/4
  size_t idx = (size_t)tid * 4;
  int d = idx & 511;
  int l = (idx >> 9) & 4095;
  int b = idx >> 21;
  float4 p = *(const float4*)(pz + b*DM + d);
  float4 pe = *(const float4*)(pos + (size_t)l*DM + d);
  float4 r;
  r.x = p.x + pe.x; r.y = p.y + pe.y;
  r.z = p.z + pe.z; r.w = p.w + pe.w;
  *(float4*)(x + idx) = r;
}

// ---------- K2: pass-1 — local chunk end states ----------
// r3 scalar body; waves_per_eu(2,2) raises VGPR budget to 256 -> no spills.
__global__ __launch_bounds__(256) __attribute__((amdgpu_waves_per_eu(2,2)))
void k_pass1(const float* __restrict__ x, const float* __restrict__ coef,
             float* __restrict__ states, int ly){
  int tid = blockIdx.x * 256 + threadIdx.x;          // (b*NCH + c)*DM + h
  int h = tid & (DM-1);
  int c = (tid >> 9) & (NCH-1);
  int b = tid >> 13;
  float wre[NST], wim[NST], sre[NST], sim[NST];
  #pragma unroll
  for (int n = 0; n < NST; ++n){
    int o = ((ly*NST + n) << 9) + h;
    wre[n] = coef[0*SZC + o];
    wim[n] = coef[1*SZC + o];
    sre[n] = 0.f; sim[n] = 0.f;
  }
  const float* up = x + (size_t)((b << 12) + c*TC) * DM + h;
  #pragma unroll 2
  for (int t = 0; t < TC; ++t){
    float u = up[(size_t)t << 9];
    #pragma unroll
    for (int n = 0; n < NST; ++n){
      float nr = fmaf(wre[n], sre[n], fmaf(-wim[n], sim[n], u));
      float ni = fmaf(wim[n], sre[n], wre[n]*sim[n]);
      sre[n] = nr; sim[n] = ni;
    }
  }
  float* sp = states + (size_t)((b*NCH + c)*64) * DM + h;
  #pragma unroll
  for (int n = 0; n < NST; ++n){
    sp[n << 9]          = sre[n];
    sp[(NST + n) << 9]  = sim[n];
  }
}

// ---------- K3: scan over chunks -> start states (in place) ----------
__global__ void k_scan(const float* coef, float* states, int ly){
  int tid = blockIdx.x * 256 + threadIdx.x;          // (b*NST + n)*DM + h
  int h = tid & (DM-1);
  int n = (tid >> 9) & (NST-1);
  int b = tid >> 14;
  int o = ((ly*NST + n) << 9) + h;
  float wTre = coef[4*SZC + o];
  float wTim = coef[5*SZC + o];
  float Sre = 0.f, Sim = 0.f;
  for (int c = 0; c < NCH; ++c){
    float* pr = states + (size_t)((b*NCH + c)*64 + n) * DM + h;
    float lr = pr[0];
    float li = pr[NST << 9];
    pr[0]         = Sre;           // start state for chunk c
    pr[NST << 9]  = Sim;
    float nr = fmaf(wTre, Sre, fmaf(-wTim, Sim, lr));
    float ni = fmaf(wTre, Sim, fmaf( wTim, Sre, li));
    Sre = nr; Sim = ni;
  }
}

// ---------- K4: pass-2 — replay + y + D-skip + GELU -> ybuf (bf16) ----------
__global__ __launch_bounds__(256) __attribute__((amdgpu_waves_per_eu(2,2)))
void k_pass2(const float* __restrict__ x, const float* __restrict__ coef,
             const float* __restrict__ states, const float* __restrict__ Dsk,
             unsigned short* __restrict__ ybuf, int ly){
  int tid = blockIdx.x * 256 + threadIdx.x;          // (b*NCH + c)*DM + h
  int h = tid & (DM-1);
  int c = (tid >> 9) & (NCH-1);
  int b = tid >> 13;
  float wre[NST], wim[NST], c2r[NST], c2i[NST], sre[NST], sim[NST];
  const float* sp = states + (size_t)((b*NCH + c)*64) * DM + h;
  #pragma unroll
  for (int n = 0; n < NST; ++n){
    int o = ((ly*NST + n) << 9) + h;
    wre[n] = coef[0*SZC + o];
    wim[n] = coef[1*SZC + o];
    c2r[n] = coef[2*SZC + o];
    c2i[n] = coef[3*SZC + o];      // already negated
    sre[n] = sp[n << 9];
    sim[n] = sp[(NST + n) << 9];
  }
  float Dv = Dsk[ly*DM + h];
  const float* up = x + (size_t)((b << 12) + c*TC) * DM + h;
  unsigned short* yp = ybuf + (size_t)((b << 12) + c*TC) * DM + h;
  #pragma unroll 2
  for (int t = 0; t < TC; ++t){
    float u = up[(size_t)t << 9];
    float y = 0.f;
    #pragma unroll
    for (int n = 0; n < NST; ++n){
      float nr = fmaf(wre[n], sre[n], fmaf(-wim[n], sim[n], u));
      float ni = fmaf(wim[n], sre[n], wre[n]*sim[n]);
      sre[n] = nr; sim[n] = ni;
      y = fmaf(c2r[n], nr, fmaf(c2i[n], ni, y));
    }
    y = fmaf(Dv, u, y);
    float g = 0.5f * y * (1.0f + erff(y * 0.70710678118654752f));
    yp[(size_t)t << 9] = f2us(g);
  }
}

// ---------- K5: GEMM (M=B*L, N=512 x both GLU halves, K=512) + GLU + residual ----------
__global__ __launch_bounds__(256,2) void k_gemm(const unsigned short* A, const unsigned short* Bw,
                                                const float* bias, float* x, int ly){
  __shared__ short As[128*64];
  __shared__ short Bs[2][128*64];
  const int K = 512;
  int Mt = blockIdx.x >> 2;        // 512 m-tiles of 128 rows
  int Nt = blockIdx.x & 3;         // 4 n-tiles of 128 cols (each also covers +512 half)
  int lane = threadIdx.x & 63, wv = threadIdx.x >> 6;
  int wm = wv >> 1, wn = wv & 1;
  f32x4 acc[2][4][4] = {};
  const unsigned short* Ag = A  + (size_t)Mt * 128 * K;
  const unsigned short* B0 = Bw + (size_t)ly * 1024 * K + (size_t)Nt * 128 * K;
  const unsigned short* B1 = B0 + (size_t)512 * K;
  for (int k0 = 0; k0 < K; k0 += 64){
    __syncthreads();
    #pragma unroll
    for (int p = 0; p < 4; ++p){
      int e = (p*256 + threadIdx.x) * 8;     // element idx in 128x64 tile
      int row = e >> 6, k = e & 63;
      int sw = ((k >> 3) ^ (row & 7)) << 3;  // XOR swizzle, conflict-reduced reads
      *(uint4*)(&As[row*64 + sw])    = *(const uint4*)(Ag + (size_t)row*K + k0 + k);
      *(uint4*)(&Bs[0][row*64 + sw]) = *(const uint4*)(B0 + (size_t)row*K + k0 + k);
      *(uint4*)(&Bs[1][row*64 + sw]) = *(const uint4*)(B1 + (size_t)row*K + k0 + k);
    }
    __syncthreads();
    #pragma unroll
    for (int kk = 0; kk < 64; kk += 32){
      int kb = (kk >> 3) + (lane >> 4);
      bf16x8 af[4], b0[4], b1[4];
      #pragma unroll
      for (int i = 0; i < 4; ++i){
        int ra = wm*64 + i*16 + (lane & 15);
        af[i] = *(const bf16x8*)(&As[ra*64 + ((kb ^ (ra & 7)) << 3)]);
        int rb = wn*64 + i*16 + (lane & 15);
        b0[i] = *(const bf16x8*)(&Bs[0][rb*64 + ((kb ^ (rb & 7)) << 3)]);
        b1[i] = *(const bf16x8*)(&Bs[1][rb*64 + ((kb ^ (rb & 7)) << 3)]);
      }
      #pragma unroll
      for (int i = 0; i < 4; ++i)
        #pragma unroll
        for (int j = 0; j < 4; ++j){
          acc[0][i][j] = __builtin_amdgcn_mfma_f32_16x16x32_bf16(af[i], b0[j], acc[0][i][j], 0, 0, 0);
          acc[1][i][j] = __builtin_amdgcn_mfma_f32_16x16x32_bf16(af[i], b1[j], acc[1][i][j], 0, 0, 0);
        }
    }
  }
  // epilogue: bias + GLU + residual add into x (fp32, in place)
  #pragma unroll
  for (int j = 0; j < 4; ++j){
    int n = Nt*128 + wn*64 + j*16 + (lane & 15);       // 0..511
    float ba = bias[ly*1024 + n];
    float bg = bias[ly*1024 + 512 + n];
    #pragma unroll
    for (int i = 0; i < 4; ++i){
      int mb = Mt*128 + wm*64 + i*16 + ((lane >> 4) << 2);
      #pragma unroll
      for (int q = 0; q < 4; ++q){
        float a = acc[0][i][j][q] + ba;
        float g = acc[1][i][j][q] + bg;
        float glu = a / (1.0f + expf(-g));
        size_t off = (size_t)(mb + q) * DM + n;
        x[off] += glu;
      }
    }
  }
}

// ---------- K7: LayerNorm over D (wave per row) ----------
__global__ __launch_bounds__(256) void k_ln(float* x, const float* gam,
                                            const float* bet, int ly){
  int row = blockIdx.x*4 + (threadIdx.x >> 6);
  int lane = threadIdx.x & 63;
  float* xr = x + (size_t)row * DM + lane*8;
  float4 v0 = *(const float4*)xr;
  float4 v1 = *(const float4*)(xr + 4);
  float s  = v0.x+v0.y+v0.z+v0.w + v1.x+v1.y+v1.z+v1.w;
  float s2 = v0.x*v0.x+v0.y*v0.y+v0.z*v0.z+v0.w*v0.w
           + v1.x*v1.x+v1.y*v1.y+v1.z*v1.z+v1.w*v1.w;
  #pragma unroll
  for (int m = 32; m > 0; m >>= 1){
    s  += __shfl_xor(s,  m, 64);
    s2 += __shfl_xor(s2, m, 64);
  }
  float mu  = s * (1.0f/DM);
  float var = s2 * (1.0f/DM) - mu*mu;
  float rs  = rsqrtf(var + 1e-5f);
  const float* gp  = gam + ly*DM + lane*8;
  const float* bp2 = bet + ly*DM + lane*8;
  float4 g0 = *(const float4*)gp,  g1 = *(const float4*)(gp + 4);
  float4 b0 = *(const float4*)bp2, b1 = *(const float4*)(bp2 + 4);
  v0.x = (v0.x-mu)*rs*g0.x + b0.x;
  v0.y = (v0.y-mu)*rs*g0.y + b0.y;
  v0.z = (v0.z-mu)*rs*g0.z + b0.z;
  v0.w = (v0.w-mu)*rs*g0.w + b0.w;
  v1.x = (v1.x-mu)*rs*g1.x + b1.x;
  v1.y = (v1.y-mu)*rs*g1.y + b1.y;
  v1.z = (v1.z-mu)*rs*g1.z + b1.z;
  v1.w = (v1.w-mu)*rs*g1.w + b1.w;
  *(float4*)xr       = v0;
  *(float4*)(xr + 4) = v1;
}

// ---------- K8: final projection to (mu, log_sig), fp32 out ----------
__global__ __launch_bounds__(256) void k_out(const float* x, const float* Wpx,
                                             const float* bpx, float* out){
  int row = blockIdx.x*4 + (threadIdx.x >> 6);        // b*4096 + l
  int lane = threadIdx.x & 63;
  const float* xr = x + (size_t)row * DM + lane*8;
  float4 v0 = *(const float4*)xr;
  float4 v1 = *(const float4*)(xr + 4);
  float p[6];
  #pragma unroll
  for (int c = 0; c < 6; ++c){
    const float* wr = Wpx + c*DM + lane*8;
    float4 w0 = *(const float4*)wr, w1 = *(const float4*)(wr + 4);
    float s = v0.x*w0.x + v0.y*w0.y + v0.z*w0.z + v0.w*w0.w
            + v1.x*w1.x + v1.y*w1.y + v1.z*w1.z + v1.w*w1.w;
    #pragma unroll
    for (int m = 32; m > 0; m >>= 1) s += __shfl_xor(s, m, 64);
    p[c] = s;
  }
  if (lane == 0){
    int b = row >> 12, l = row & 4095;
    #pragma unroll
    for (int c = 0; c < 3; ++c)
      out[((b*3 + c) << 12) + l] = p[c] + bpx[c];
    #pragma unroll
    for (int c = 3; c < 6; ++c)
      out[B_*3*LSEQ + ((b*3 + (c-3)) << 12) + l] = p[c] + bpx[c];
  }
}

// ---------- launcher ----------
extern "C" void kernel_launch(void* const* d_in, const int* in_sizes, int n_in,
                              void* d_out, int out_size, void* d_ws, size_t ws_size,
                              hipStream_t stream) {
  const float* z     = (const float*)d_in[0];
  const float* Wp    = (const float*)d_in[1];
  const float* bp    = (const float*)d_in[2];
  const float* pos   = (const float*)d_in[3];
  const float* logdt = (const float*)d_in[4];
  const float* Cre   = (const float*)d_in[5];
  const float* Cim   = (const float*)d_in[6];
  const float* lAr   = (const float*)d_in[7];
  const float* Aimg  = (const float*)d_in[8];
  const float* Dsk   = (const float*)d_in[9];
  const float* Wc    = (const float*)d_in[10];
  const float* bc    = (const float*)d_in[11];
  const float* lng   = (const float*)d_in[12];
  const float* lnb   = (const float*)d_in[13];
  const float* Wpx   = (const float*)d_in[14];
  const float* bpx   = (const float*)d_in[15];
  float* out = (float*)d_out;

  char* ws = (char*)d_ws;
  const size_t XB = (size_t)B_ * LSEQ * DM * 4;       // 134217728 : x fp32
  const size_t YB = (size_t)B_ * LSEQ * DM * 2;       // 67108864  : ybuf bf16
  const size_t SB = (size_t)B_ * NCH * 64 * DM * 4;   // 33554432  : states fp32
  const size_t CB = (size_t)6 * SZC * 4;              // 1572864   : coef
  const size_t PB = (size_t)B_ * DM * 4;              // 32768     : pz
  float*          x      = (float*)ws;
  unsigned short* ybuf   = (unsigned short*)(ws + XB);
  float*          states = (float*)(ws + XB + YB);
  float*          cf     = (float*)(ws + XB + YB + SB);
  float*          pz     = (float*)(ws + XB + YB + SB + CB);
  unsigned short* Wcb    = (unsigned short*)(ws + XB + YB + SB + CB + PB);
  // total = 240,680,960 bytes

  k_coef <<<256,   256, 0, stream>>>(logdt, Cre, Cim, lAr, Aimg, cf);
  k_cvt  <<<1024,  256, 0, stream>>>(Wc, Wcb);
  k_proj <<<32,    256, 0, stream>>>(z, Wp, bp, pz);
  k_bcast<<<32768, 256, 0, stream>>>(pz, pos, x);
  for (int ly = 0; ly < NL; ++ly){
    k_pass1<<<512,  256, 0, stream>>>(x, cf, states, ly);
    k_scan <<<1024, 256, 0, stream>>>(cf, states, ly);
    k_pass2<<<512,  256, 0, stream>>>(x, cf, states, Dsk, ybuf, ly);
    k_gemm <<<2048, 256, 0, stream>>>(ybuf, Wcb, bc, x, ly);
    k_ln   <<<16384,256, 0, stream>>>(x, lng, lnb, ly);
  }
  k_out<<<16384, 256, 0, stream>>>(x, Wpx, bpx, out);
}